// Round 1
// baseline (519.210 us; speedup 1.0000x reference)
//
#include <hip/hip_runtime.h>

#define N_NODES 100000
#define N_EDGES 1600000
#define D 64

__global__ void init_deg_kernel(float* __restrict__ deg) {
    int i = blockIdx.x * blockDim.x + threadIdx.x;
    if (i < N_NODES) deg[i] = 1.0f;  // self-loop contributes 1
}

__global__ void accum_deg_kernel(const int* __restrict__ ei, float* __restrict__ deg) {
    int e = blockIdx.x * blockDim.x + threadIdx.x;
    if (e < N_EDGES) {
        int r = ei[e];
        int c = ei[N_EDGES + e];
        if (r != c) atomicAdd(&deg[r], 1.0f);
    }
}

__global__ void dinv_kernel(const float* __restrict__ deg, float* __restrict__ dinv) {
    int i = blockIdx.x * blockDim.x + threadIdx.x;
    if (i < N_NODES) dinv[i] = rsqrtf(deg[i]);
}

// out[i][d] = x[i][d] * dinv[i]^2   (self-loop term; also clears the 0xAA poison)
__global__ void init_out_kernel(const float* __restrict__ x, const float* __restrict__ dinv,
                                float* __restrict__ out) {
    int idx = blockIdx.x * blockDim.x + threadIdx.x;
    if (idx < N_NODES * D) {
        int i = idx >> 6;
        float di = dinv[i];
        out[idx] = x[idx] * di * di;
    }
}

// One wave (64 lanes) per edge: lane d handles feature d.
__global__ void scatter_kernel(const int* __restrict__ ei, const float* __restrict__ x,
                               const float* __restrict__ dinv, float* __restrict__ out) {
    int t = blockIdx.x * blockDim.x + threadIdx.x;
    int e = t >> 6;       // wave-uniform
    int d = t & (D - 1);  // lane id
    if (e < N_EDGES) {
        int r = ei[e];
        int c = ei[N_EDGES + e];
        if (r != c) {
            float coef = dinv[r] * dinv[c];
            atomicAdd(&out[r * D + d], coef * x[c * D + d]);
        }
    }
}

extern "C" void kernel_launch(void* const* d_in, const int* in_sizes, int n_in,
                              void* d_out, int out_size, void* d_ws, size_t ws_size,
                              hipStream_t stream) {
    const float* x = (const float*)d_in[0];
    const int* ei = (const int*)d_in[1];
    float* out = (float*)d_out;

    float* deg = (float*)d_ws;
    float* dinv = deg + N_NODES;

    init_deg_kernel<<<(N_NODES + 255) / 256, 256, 0, stream>>>(deg);
    accum_deg_kernel<<<(N_EDGES + 255) / 256, 256, 0, stream>>>(ei, deg);
    dinv_kernel<<<(N_NODES + 255) / 256, 256, 0, stream>>>(deg, dinv);
    init_out_kernel<<<(N_NODES * D + 255) / 256, 256, 0, stream>>>(x, dinv, out);
    scatter_kernel<<<(N_EDGES * D + 255) / 256, 256, 0, stream>>>(ei, x, dinv, out);
}

// Round 2
// 364.325 us; speedup vs baseline: 1.4251x; 1.4251x over previous
//
#include <hip/hip_runtime.h>

#define N_NODES 100000
#define N_EDGES 1600000
#define D 64
#define SCAN_B 256
#define NBLK ((N_NODES + SCAN_B - 1) / SCAN_B)   // 391

// ---- pass 1: zero int degree counters ----
__global__ void zero_cnt_kernel(int* __restrict__ cnt) {
    int i = blockIdx.x * blockDim.x + threadIdx.x;
    if (i < N_NODES) cnt[i] = 0;
}

// ---- pass 2: histogram of rows (non-self edges) ----
__global__ void hist_kernel(const int* __restrict__ ei, int* __restrict__ cnt) {
    int e = blockIdx.x * blockDim.x + threadIdx.x;
    if (e < N_EDGES) {
        int r = ei[e];
        int c = ei[N_EDGES + e];
        if (r != c) atomicAdd(&cnt[r], 1);
    }
}

// ---- pass 3a: per-block exclusive scan of cnt into rowptr; block totals out ----
__global__ void scan1_kernel(const int* __restrict__ cnt, int* __restrict__ rowptr,
                             int* __restrict__ blocksums) {
    __shared__ int s[SCAN_B];
    int i = blockIdx.x * SCAN_B + threadIdx.x;
    int v = (i < N_NODES) ? cnt[i] : 0;
    s[threadIdx.x] = v;
    __syncthreads();
    for (int off = 1; off < SCAN_B; off <<= 1) {
        int t = (threadIdx.x >= off) ? s[threadIdx.x - off] : 0;
        __syncthreads();
        s[threadIdx.x] += t;
        __syncthreads();
    }
    if (i < N_NODES) rowptr[i] = s[threadIdx.x] - v;  // exclusive within block
    if (threadIdx.x == SCAN_B - 1) blocksums[blockIdx.x] = s[SCAN_B - 1];
}

// ---- pass 3b: scan of block sums (single block, 512 >= NBLK=391) ----
__global__ void scan2_kernel(int* __restrict__ blocksums, int* __restrict__ rowptr) {
    __shared__ int s[512];
    int t = threadIdx.x;
    int v = (t < NBLK) ? blocksums[t] : 0;
    s[t] = v;
    __syncthreads();
    for (int off = 1; off < 512; off <<= 1) {
        int u = (t >= off) ? s[t - off] : 0;
        __syncthreads();
        s[t] += u;
        __syncthreads();
    }
    if (t < NBLK) blocksums[t] = s[t] - v;            // exclusive
    if (t == NBLK - 1) rowptr[N_NODES] = s[t];        // total edge count E'
}

// ---- pass 3c: add block offsets; init cursor; compute dinv ----
__global__ void scan3_kernel(const int* __restrict__ cnt, int* __restrict__ rowptr,
                             const int* __restrict__ blocksums, int* __restrict__ cursor,
                             float* __restrict__ dinv) {
    int i = blockIdx.x * blockDim.x + threadIdx.x;
    if (i < N_NODES) {
        int rp = rowptr[i] + blocksums[i / SCAN_B];
        rowptr[i] = rp;
        cursor[i] = rp;
        dinv[i] = rsqrtf((float)(1 + cnt[i]));   // self-loop contributes 1
    }
}

// ---- pass 4: bucket edges by row ----
__global__ void bucket_kernel(const int* __restrict__ ei, int* __restrict__ cursor,
                              int* __restrict__ sortedCol) {
    int e = blockIdx.x * blockDim.x + threadIdx.x;
    if (e < N_EDGES) {
        int r = ei[e];
        int c = ei[N_EDGES + e];
        if (r != c) {
            int p = atomicAdd(&cursor[r], 1);
            sortedCol[p] = c;
        }
    }
}

// ---- pass 5: gather. One wave (64 lanes) per row, lane d = feature d ----
__global__ void gather_kernel(const float* __restrict__ x, const float* __restrict__ dinv,
                              const int* __restrict__ rowptr, const int* __restrict__ sortedCol,
                              float* __restrict__ out) {
    int t = blockIdx.x * blockDim.x + threadIdx.x;
    int r = t >> 6;
    int d = t & 63;
    if (r >= N_NODES) return;
    int start = rowptr[r];
    int end = rowptr[r + 1];
    float dr = dinv[r];
    float acc = dr * x[r * D + d];              // self-loop term (÷ final dr → dr^2)
    for (int j = start; j < end; j += 64) {
        int idx = j + d;                         // lanes cooperatively prefetch edges
        int cj = 0;
        float dj = 0.f;
        if (idx < end) {
            cj = sortedCol[idx];
            dj = dinv[cj];
        }
        int n = min(64, end - j);
        for (int k = 0; k < n; k++) {
            int c = __shfl(cj, k);
            float dc = __shfl(dj, k);
            acc += dc * x[c * D + d];
        }
    }
    out[r * D + d] = dr * acc;
}

extern "C" void kernel_launch(void* const* d_in, const int* in_sizes, int n_in,
                              void* d_out, int out_size, void* d_ws, size_t ws_size,
                              hipStream_t stream) {
    const float* x = (const float*)d_in[0];
    const int* ei = (const int*)d_in[1];
    float* out = (float*)d_out;

    // workspace layout (all 4-byte elems): ~8.0 MB total
    int* cnt = (int*)d_ws;                    // [N_NODES]
    int* rowptr = cnt + N_NODES;              // [N_NODES+1]
    int* blocksums = rowptr + N_NODES + 1;    // [512]
    int* cursor = blocksums + 512;            // [N_NODES]
    int* sortedCol = cursor + N_NODES;        // [N_EDGES]
    float* dinv = (float*)(sortedCol + N_EDGES); // [N_NODES]

    zero_cnt_kernel<<<(N_NODES + 255) / 256, 256, 0, stream>>>(cnt);
    hist_kernel<<<(N_EDGES + 255) / 256, 256, 0, stream>>>(ei, cnt);
    scan1_kernel<<<NBLK, SCAN_B, 0, stream>>>(cnt, rowptr, blocksums);
    scan2_kernel<<<1, 512, 0, stream>>>(blocksums, rowptr);
    scan3_kernel<<<(N_NODES + 255) / 256, 256, 0, stream>>>(cnt, rowptr, blocksums, cursor, dinv);
    bucket_kernel<<<(N_EDGES + 255) / 256, 256, 0, stream>>>(ei, cursor, sortedCol);
    gather_kernel<<<(N_NODES * D + 255) / 256, 256, 0, stream>>>(x, dinv, rowptr, sortedCol, out);
}

// Round 3
// 223.936 us; speedup vs baseline: 2.3186x; 1.6269x over previous
//
#include <hip/hip_runtime.h>

#define N_NODES 100000
#define N_EDGES 1600000
#define D 64
#define NB 391            // row buckets of 256 rows: (100000+255)/256
#define PBLK 256          // partition blocks
#define CHUNK ((N_EDGES + PBLK - 1) / PBLK)   // 6250 edges per partition block
#define FLATN (NB * PBLK) // 100096 count-matrix entries
#define SB1 ((FLATN + 255) / 256)             // 391 scan blocks

// ---- pass 1: per-(block,bucket) edge counts via LDS histogram ----
__global__ void count_kernel(const int* __restrict__ ei, int* __restrict__ counts) {
    __shared__ int h[NB];
    for (int i = threadIdx.x; i < NB; i += 256) h[i] = 0;
    __syncthreads();
    int s = blockIdx.x * CHUNK;
    int e = min(s + CHUNK, N_EDGES);
    for (int i = s + (int)threadIdx.x; i < e; i += 256) {
        int r = ei[i], c = ei[N_EDGES + i];
        if (r != c) atomicAdd(&h[r >> 8], 1);
    }
    __syncthreads();
    // transposed layout: counts[bucket*PBLK + block] so the scan is bucket-major
    for (int i = threadIdx.x; i < NB; i += 256) counts[i * PBLK + blockIdx.x] = h[i];
}

// ---- pass 2a: per-block exclusive scan (in place) over the flat count matrix ----
__global__ void scan1_kernel(int* __restrict__ a, int* __restrict__ blocksums) {
    __shared__ int s[256];
    int i = blockIdx.x * 256 + threadIdx.x;
    int v = (i < FLATN) ? a[i] : 0;
    s[threadIdx.x] = v;
    __syncthreads();
    for (int off = 1; off < 256; off <<= 1) {
        int t = (threadIdx.x >= off) ? s[threadIdx.x - off] : 0;
        __syncthreads();
        s[threadIdx.x] += t;
        __syncthreads();
    }
    if (i < FLATN) a[i] = s[threadIdx.x] - v;
    if (threadIdx.x == 255) blocksums[blockIdx.x] = s[255];
}

// ---- pass 2b: scan block sums (SB1=391 <= 512); total -> rowptr[N_NODES] ----
__global__ void scan2_kernel(int* __restrict__ blocksums, int* __restrict__ rowptr) {
    __shared__ int s[512];
    int t = threadIdx.x;
    int v = (t < SB1) ? blocksums[t] : 0;
    s[t] = v;
    __syncthreads();
    for (int off = 1; off < 512; off <<= 1) {
        int u = (t >= off) ? s[t - off] : 0;
        __syncthreads();
        s[t] += u;
        __syncthreads();
    }
    if (t < SB1) blocksums[t] = s[t] - v;
    if (t == SB1 - 1) rowptr[N_NODES] = s[t];  // total non-self edges
}

// ---- pass 2c: add back block offsets ----
__global__ void scan3_kernel(int* __restrict__ a, const int* __restrict__ blocksums) {
    int i = blockIdx.x * blockDim.x + threadIdx.x;
    if (i < FLATN) a[i] += blocksums[i >> 8];
}

// ---- pass 3: partition scatter. Each block owns contiguous runs per bucket ->
//      lines are written by one XCD only and coalesce in L2. ----
__global__ void scatter_part_kernel(const int* __restrict__ ei, const int* __restrict__ offsets,
                                    int* __restrict__ epack) {
    __shared__ int cur[NB];
    for (int i = threadIdx.x; i < NB; i += 256) cur[i] = offsets[i * PBLK + blockIdx.x];
    __syncthreads();
    int s = blockIdx.x * CHUNK;
    int e = min(s + CHUNK, N_EDGES);
    for (int i = s + (int)threadIdx.x; i < e; i += 256) {
        int r = ei[i], c = ei[N_EDGES + i];
        if (r != c) {
            int p = atomicAdd(&cur[r >> 8], 1);
            epack[p] = ((r & 255) << 17) | c;   // c < 2^17, rlow 8 bits
        }
    }
}

// ---- pass 4: per-bucket LDS counting sort by row; emit rowptr, dinv, sortedCol ----
__global__ void rowsort_kernel(const int* __restrict__ offsets, const int* __restrict__ rowptr_last,
                               const int* __restrict__ epack, int* __restrict__ rowptr,
                               float* __restrict__ dinv, int* __restrict__ sortedCol) {
    __shared__ int h[256];
    __shared__ int sc[256];
    __shared__ int cur[256];
    int b = blockIdx.x;
    int t = threadIdx.x;
    int base = offsets[b * PBLK];
    int end = (b + 1 < NB) ? offsets[(b + 1) * PBLK] : rowptr_last[N_NODES];
    h[t] = 0;
    __syncthreads();
    for (int i = base + t; i < end; i += 256) atomicAdd(&h[epack[i] >> 17], 1);
    __syncthreads();
    int v = h[t];
    sc[t] = v;
    __syncthreads();
    for (int off = 1; off < 256; off <<= 1) {
        int u = (t >= off) ? sc[t - off] : 0;
        __syncthreads();
        sc[t] += u;
        __syncthreads();
    }
    int excl = sc[t] - v;
    int row = b * 256 + t;
    if (row < N_NODES) {
        rowptr[row] = base + excl;
        dinv[row] = rsqrtf((float)(1 + v));   // +1 for the self-loop
    }
    cur[t] = base + excl;
    __syncthreads();
    for (int i = base + t; i < end; i += 256) {
        int p = epack[i];
        int pos = atomicAdd(&cur[p >> 17], 1);
        sortedCol[pos] = p & 0x1FFFF;
    }
}

// ---- pass 5: gather. One wave per row, lane d = feature d ----
__global__ void gather_kernel(const float* __restrict__ x, const float* __restrict__ dinv,
                              const int* __restrict__ rowptr, const int* __restrict__ sortedCol,
                              float* __restrict__ out) {
    int t = blockIdx.x * blockDim.x + threadIdx.x;
    int r = t >> 6;
    int d = t & 63;
    if (r >= N_NODES) return;
    int start = rowptr[r];
    int end = rowptr[r + 1];
    float dr = dinv[r];
    float acc = dr * x[r * D + d];              // self-loop term (x final dr -> dr^2)
    for (int j = start; j < end; j += 64) {
        int idx = j + d;                         // lanes cooperatively prefetch edges
        int cj = 0;
        float dj = 0.f;
        if (idx < end) {
            cj = sortedCol[idx];
            dj = dinv[cj];
        }
        int n = min(64, end - j);
        for (int k = 0; k < n; k++) {
            int c = __shfl(cj, k);
            float dc = __shfl(dj, k);
            acc += dc * x[c * D + d];
        }
    }
    out[r * D + d] = dr * acc;
}

extern "C" void kernel_launch(void* const* d_in, const int* in_sizes, int n_in,
                              void* d_out, int out_size, void* d_ws, size_t ws_size,
                              hipStream_t stream) {
    const float* x = (const float*)d_in[0];
    const int* ei = (const int*)d_in[1];
    float* out = (float*)d_out;

    // workspace layout (~14.0 MB)
    int* offsets = (int*)d_ws;                 // [FLATN] count matrix -> scanned offsets
    int* blocksums = offsets + FLATN;          // [512]
    int* rowptr = blocksums + 512;             // [N_NODES+1]
    float* dinv = (float*)(rowptr + N_NODES + 1); // [N_NODES]
    int* epack = (int*)(dinv + N_NODES);       // [N_EDGES]
    int* sortedCol = epack + N_EDGES;          // [N_EDGES]

    count_kernel<<<PBLK, 256, 0, stream>>>(ei, offsets);
    scan1_kernel<<<SB1, 256, 0, stream>>>(offsets, blocksums);
    scan2_kernel<<<1, 512, 0, stream>>>(blocksums, rowptr);
    scan3_kernel<<<(FLATN + 255) / 256, 256, 0, stream>>>(offsets, blocksums);
    scatter_part_kernel<<<PBLK, 256, 0, stream>>>(ei, offsets, epack);
    rowsort_kernel<<<NB, 256, 0, stream>>>(offsets, rowptr, epack, rowptr, dinv, sortedCol);
    gather_kernel<<<(N_NODES * D + 255) / 256, 256, 0, stream>>>(x, dinv, rowptr, sortedCol, out);
}